// Round 5
// baseline (565.083 us; speedup 1.0000x reference)
//
#include <hip/hip_runtime.h>

// DopamineArea: out_spikes = (spikes >= 0.5); S = mean(out_spikes); delta = S - P.
// Output layout: d_out[0..N) = delta, d_out[N..2N) = out_spikes.
// Roofline: 512 MiB mandatory HBM traffic -> ~85 us floor at 6.3 TB/s.
//
// R1: 32768 same-line atomicAdds serialized k1 at 380 us (NOT dispatch ovh).
// R3/R4: two-kernel versions plateau at dur=433 us; per-kernel <165 us each,
//   => either ~1.6 TB/s per-phase cap or ~100 us inter-kernel overhead.
// R5: FUSE into one kernel with a device-atomic grid barrier to remove the
//   second launch + inter-kernel flush and get one unambiguous kernel time.
//   1024 blocks x 256 thr = 4 blocks/CU (2x co-residency margin: ~10 VGPR,
//   1 KB LDS, limit is 8/CU) -> all blocks resident; spin barrier safe.

#define THRESH 0.5f
#define BLOCK  256
#define GRID   1024

typedef float v4f __attribute__((ext_vector_type(4)));

__device__ __forceinline__ int spike4(const v4f s, v4f& o) {
    o.x = (s.x >= THRESH) ? 1.0f : 0.0f;
    o.y = (s.y >= THRESH) ? 1.0f : 0.0f;
    o.z = (s.z >= THRESH) ? 1.0f : 0.0f;
    o.w = (s.w >= THRESH) ? 1.0f : 0.0f;
    return (int)o.x + (int)o.y + (int)o.z + (int)o.w;
}

// ws layout: ws[0] = arrive counter (zeroed by memset node); ws[64..64+GRID) = partials.
__global__ __launch_bounds__(BLOCK) void fused_kernel(
    const v4f* __restrict__ spikes4,
    const v4f* __restrict__ P4,
    v4f* __restrict__ out_spikes4,
    v4f* __restrict__ delta4,
    unsigned int* ws,
    int chunk, float inv_n)
{
    unsigned int* arrive   = ws;
    unsigned int* partials = ws + 64;   // separate cache line from the spin word

    const int tid   = threadIdx.x;
    const int start = blockIdx.x * chunk;
    const int end   = start + chunk;

    // ---- Phase A: spikes -> out_spikes, count ----
    int cnt = 0;
    int i = start + tid;
    for (; i + 3 * BLOCK < end; i += 4 * BLOCK) {
        v4f a = spikes4[i];
        v4f b = spikes4[i +     BLOCK];
        v4f c = spikes4[i + 2 * BLOCK];
        v4f d = spikes4[i + 3 * BLOCK];
        v4f oa, ob, oc, od;
        cnt += spike4(a, oa);
        cnt += spike4(b, ob);
        cnt += spike4(c, oc);
        cnt += spike4(d, od);
        out_spikes4[i]             = oa;
        out_spikes4[i +     BLOCK] = ob;
        out_spikes4[i + 2 * BLOCK] = oc;
        out_spikes4[i + 3 * BLOCK] = od;
    }
    for (; i < end; i += BLOCK) {
        v4f s = spikes4[i];
        v4f o;
        cnt += spike4(s, o);
        out_spikes4[i] = o;
    }

    // Block reduction of cnt.
    #pragma unroll
    for (int off = 32; off > 0; off >>= 1)
        cnt += __shfl_down(cnt, off, 64);
    __shared__ int wave_sums[BLOCK / 64];
    if ((tid & 63) == 0) wave_sums[tid >> 6] = cnt;
    __syncthreads();

    // ---- Grid barrier (device-scope atomics; all blocks co-resident) ----
    if (tid == 0) {
        int total = wave_sums[0] + wave_sums[1] + wave_sums[2] + wave_sums[3];
        atomicExch(&partials[blockIdx.x], (unsigned int)total); // to coherence point
        __threadfence();                                        // partial before arrive
        atomicAdd(arrive, 1u);
        while (atomicAdd(arrive, 0u) < (unsigned int)gridDim.x)
            __builtin_amdgcn_s_sleep(2);
    }
    __syncthreads();

    // ---- Reduce partials (GRID u32, L3-hot) ----
    int c = 0;
    for (int j = tid; j < GRID; j += BLOCK)
        c += (int)__hip_atomic_load(&partials[j], __ATOMIC_RELAXED,
                                    __HIP_MEMORY_SCOPE_AGENT);
    #pragma unroll
    for (int off = 32; off > 0; off >>= 1)
        c += __shfl_down(c, off, 64);
    __shared__ int wave_sums2[BLOCK / 64];
    if ((tid & 63) == 0) wave_sums2[tid >> 6] = c;
    __syncthreads();
    const int total = wave_sums2[0] + wave_sums2[1] + wave_sums2[2] + wave_sums2[3];
    const float S = (float)total * inv_n;   // exact: total <= 2^25, inv_n = 2^-25

    // ---- Phase B: delta = S - P ----
    i = start + tid;
    for (; i + 3 * BLOCK < end; i += 4 * BLOCK) {
        v4f a  = P4[i];
        v4f b  = P4[i +     BLOCK];
        v4f c4 = P4[i + 2 * BLOCK];
        v4f d  = P4[i + 3 * BLOCK];
        delta4[i]             = S - a;
        delta4[i +     BLOCK] = S - b;
        delta4[i + 2 * BLOCK] = S - c4;
        delta4[i + 3 * BLOCK] = S - d;
    }
    for (; i < end; i += BLOCK) {
        v4f p = P4[i];
        delta4[i] = S - p;
    }
}

extern "C" void kernel_launch(void* const* d_in, const int* in_sizes, int n_in,
                              void* d_out, int out_size, void* d_ws, size_t ws_size,
                              hipStream_t stream) {
    const float* spikes = (const float*)d_in[0];
    const float* P      = (const float*)d_in[1];
    float* out          = (float*)d_out;

    const int n  = in_sizes[0];          // 33554432
    const int n4 = n / 4;                // 8388608 = GRID * 8192
    const int chunk = n4 / GRID;         // 8192 v4f = 128 KiB per block

    float* delta_out  = out;             // first N floats
    float* spikes_out = out + n;         // second N floats
    unsigned int* ws  = (unsigned int*)d_ws;

    // Zero the arrive counter (d_ws is poisoned 0xAA before every launch).
    hipMemsetAsync(ws, 0, sizeof(unsigned int), stream);

    fused_kernel<<<GRID, BLOCK, 0, stream>>>(
        (const v4f*)spikes, (const v4f*)P,
        (v4f*)spikes_out, (v4f*)delta_out,
        ws, chunk, 1.0f / (float)n);
}

// Round 6
// 445.098 us; speedup vs baseline: 1.2696x; 1.2696x over previous
//
#include <hip/hip_runtime.h>

// DopamineArea: out_spikes = (spikes >= 0.5); S = mean(out_spikes); delta = S - P.
// Output layout: d_out[0..N) = delta, d_out[N..2N) = out_spikes.
// Roofline: 512 MiB mandatory HBM traffic -> ~85 us floor at 6.3 TB/s.
//
// R5 evidence: all load->compute->store loops plateau at ~1.6 TB/s
// (VALUBusy 2.4%, occ 45%) while plain fills hit 6.5 TB/s. Theory: vmcnt is
// a single in-order counter, so consuming iteration k's loads (vmcnt<=3)
// also waits for iteration k-1's STORES to drain -> each wave serializes at
// one memory round-trip per iteration. Fix: 2-deep software pipeline -- issue
// batch k+1 loads BEFORE consuming batch k, so the consume wait is vmcnt(8)
// and stores never sit on the critical path. 2048 blocks = 32 waves/CU.
// R5 also showed the grid-barrier fusion regressed dur (565 vs 433): revert
// to two kernels; partials handoff is safe via end-of-dispatch L2 writeback.

#define THRESH 0.5f
#define BLOCK  256
#define GRID   2048   // 8 blocks/CU x 256 CUs, 32 waves/CU

typedef float v4f __attribute__((ext_vector_type(4)));

__device__ __forceinline__ int spike4(const v4f s, v4f& o) {
    o.x = (s.x >= THRESH) ? 1.0f : 0.0f;
    o.y = (s.y >= THRESH) ? 1.0f : 0.0f;
    o.z = (s.z >= THRESH) ? 1.0f : 0.0f;
    o.w = (s.w >= THRESH) ? 1.0f : 0.0f;
    return (int)o.x + (int)o.y + (int)o.z + (int)o.w;
}

// Kernel 1: stream spikes -> out_spikes, one integer partial per block.
__global__ __launch_bounds__(BLOCK) void spike_count_kernel(
    const v4f* __restrict__ in,
    v4f* __restrict__ outv,
    unsigned int* __restrict__ partials,
    int n4)
{
    const int tid  = threadIdx.x;
    const int step = GRID * BLOCK;       // 524288 v4f
    int cnt = 0;

    int i  = blockIdx.x * BLOCK + tid;
    int ip = i;
    v4f a0, a1, a2, a3;
    const bool have = (i + 3 * step < n4);
    if (have) {
        a0 = in[i]; a1 = in[i + step]; a2 = in[i + 2 * step]; a3 = in[i + 3 * step];
        i += 4 * step;
    }
    while (i + 3 * step < n4) {
        // Issue next batch's loads BEFORE consuming current batch.
        v4f b0 = in[i], b1 = in[i + step], b2 = in[i + 2 * step], b3 = in[i + 3 * step];
        v4f o0, o1, o2, o3;
        cnt += spike4(a0, o0); cnt += spike4(a1, o1);
        cnt += spike4(a2, o2); cnt += spike4(a3, o3);
        outv[ip]            = o0;
        outv[ip +     step] = o1;
        outv[ip + 2 * step] = o2;
        outv[ip + 3 * step] = o3;
        a0 = b0; a1 = b1; a2 = b2; a3 = b3;
        ip = i; i += 4 * step;
    }
    if (have) {
        v4f o0, o1, o2, o3;
        cnt += spike4(a0, o0); cnt += spike4(a1, o1);
        cnt += spike4(a2, o2); cnt += spike4(a3, o3);
        outv[ip]            = o0;
        outv[ip +     step] = o1;
        outv[ip + 2 * step] = o2;
        outv[ip + 3 * step] = o3;
    }
    // Generic tail (empty for n4 = 16*step).
    for (; i < n4; i += step) {
        v4f s = in[i];
        v4f o;
        cnt += spike4(s, o);
        outv[i] = o;
    }

    // Block reduction: wave-64 shuffle -> LDS -> thread 0 stores partial.
    #pragma unroll
    for (int off = 32; off > 0; off >>= 1)
        cnt += __shfl_down(cnt, off, 64);
    __shared__ int wave_sums[BLOCK / 64];
    if ((tid & 63) == 0) wave_sums[tid >> 6] = cnt;
    __syncthreads();
    if (tid == 0) {
        int total = wave_sums[0] + wave_sums[1] + wave_sums[2] + wave_sums[3];
        partials[blockIdx.x] = (unsigned int)total;
    }
}

// Kernel 2: each block redundantly reduces the partials (8 KB, hot after the
// dispatch-boundary L2 writeback), then streams delta = S - P, same pipeline.
__global__ __launch_bounds__(BLOCK) void delta_kernel(
    const v4f* __restrict__ P4,
    v4f* __restrict__ delta4,
    const unsigned int* __restrict__ partials,
    int n4, float inv_n)
{
    const int tid = threadIdx.x;

    int c = 0;
    #pragma unroll
    for (int j = 0; j < GRID / BLOCK; ++j)
        c += (int)partials[j * BLOCK + tid];
    #pragma unroll
    for (int off = 32; off > 0; off >>= 1)
        c += __shfl_down(c, off, 64);
    __shared__ int wave_sums[BLOCK / 64];
    if ((tid & 63) == 0) wave_sums[tid >> 6] = c;
    __syncthreads();
    const int total = wave_sums[0] + wave_sums[1] + wave_sums[2] + wave_sums[3];
    const float S = (float)total * inv_n;   // exact: total <= 2^25, inv_n = 2^-25

    const int step = GRID * BLOCK;
    int i  = blockIdx.x * BLOCK + tid;
    int ip = i;
    v4f a0, a1, a2, a3;
    const bool have = (i + 3 * step < n4);
    if (have) {
        a0 = P4[i]; a1 = P4[i + step]; a2 = P4[i + 2 * step]; a3 = P4[i + 3 * step];
        i += 4 * step;
    }
    while (i + 3 * step < n4) {
        v4f b0 = P4[i], b1 = P4[i + step], b2 = P4[i + 2 * step], b3 = P4[i + 3 * step];
        delta4[ip]            = S - a0;
        delta4[ip +     step] = S - a1;
        delta4[ip + 2 * step] = S - a2;
        delta4[ip + 3 * step] = S - a3;
        a0 = b0; a1 = b1; a2 = b2; a3 = b3;
        ip = i; i += 4 * step;
    }
    if (have) {
        delta4[ip]            = S - a0;
        delta4[ip +     step] = S - a1;
        delta4[ip + 2 * step] = S - a2;
        delta4[ip + 3 * step] = S - a3;
    }
    for (; i < n4; i += step) {
        v4f p = P4[i];
        delta4[i] = S - p;
    }
}

extern "C" void kernel_launch(void* const* d_in, const int* in_sizes, int n_in,
                              void* d_out, int out_size, void* d_ws, size_t ws_size,
                              hipStream_t stream) {
    const float* spikes = (const float*)d_in[0];
    const float* P      = (const float*)d_in[1];
    float* out          = (float*)d_out;

    const int n  = in_sizes[0];          // 33554432
    const int n4 = n / 4;                // 8388608 = 16 * (GRID*BLOCK)
    float* delta_out  = out;             // first N floats
    float* spikes_out = out + n;         // second N floats

    unsigned int* partials = (unsigned int*)d_ws;  // GRID u32, fully rewritten

    spike_count_kernel<<<GRID, BLOCK, 0, stream>>>(
        (const v4f*)spikes, (v4f*)spikes_out, partials, n4);

    delta_kernel<<<GRID, BLOCK, 0, stream>>>(
        (const v4f*)P, (v4f*)delta_out, partials, n4, 1.0f / (float)n);
}

// Round 8
// 440.259 us; speedup vs baseline: 1.2835x; 1.0110x over previous
//
#include <hip/hip_runtime.h>

// DopamineArea: out_spikes = (spikes >= 0.5); S = mean(out_spikes); delta = S - P.
// Output layout: d_out[0..N) = delta, d_out[N..2N) = out_spikes.
// Roofline: ~537 MB mandatory traffic -> ~85 us floor at 6.3 TB/s.
//
// Evidence so far: ALL read+write streaming variants (1-elem/thread, chunked,
// strided, NT, pipelined; 1024-32768 blocks) plateau at ~1.6 TB/s (R5 row:
// VALUBusy 2.4%, occ 45%), while rocclr fills in the same runs do 6.5 TB/s at
// 10% occupancy (~200 blocks, grid-stride, one sliding window).
// R6: vmcnt store/load entanglement theory falsified (pipelining neutral).
// R7 theory (bench infra failed; resubmitting unchanged): the limiter is
// AGGREGATE window locality -- thousands of private per-block streams thrash
// DRAM rows/L3; the fill marches the whole grid through one few-MB sliding
// window. Mimic the fill: 512 blocks (2/CU), grid-stride, 16 KB contiguous
// per block per iteration, 8 MB grid window. Split into 3 copy-shaped kernels
// so each rocprof row isolates one regime: k1 pure-cold-read,
// k2 hot-read+write, k3 read+write.

#define THRESH 0.5f
#define BLOCK  256
#define GRID   512            // 2 blocks/CU, 8 waves/CU
#define STEP   (GRID * BLOCK * 4)   // grid advance per iteration (v4f elems)

typedef float v4f __attribute__((ext_vector_type(4)));

__device__ __forceinline__ int spike4(const v4f s, v4f& o) {
    o.x = (s.x >= THRESH) ? 1.0f : 0.0f;
    o.y = (s.y >= THRESH) ? 1.0f : 0.0f;
    o.z = (s.z >= THRESH) ? 1.0f : 0.0f;
    o.w = (s.w >= THRESH) ? 1.0f : 0.0f;
    return (int)o.x + (int)o.y + (int)o.z + (int)o.w;
}

// k1: pure streaming READ -- count spikes, one partial per block.
__global__ __launch_bounds__(BLOCK) void count_kernel(
    const v4f* __restrict__ in,
    unsigned int* __restrict__ partials,
    int n4)
{
    const int tid = threadIdx.x;
    int cnt = 0;
    int i = blockIdx.x * (BLOCK * 4) + tid;
    for (; i + 3 * BLOCK < n4; i += STEP) {
        v4f a = in[i];
        v4f b = in[i +     BLOCK];
        v4f c = in[i + 2 * BLOCK];
        v4f d = in[i + 3 * BLOCK];
        v4f t;
        cnt += spike4(a, t); cnt += spike4(b, t);
        cnt += spike4(c, t); cnt += spike4(d, t);
    }

    #pragma unroll
    for (int off = 32; off > 0; off >>= 1)
        cnt += __shfl_down(cnt, off, 64);
    __shared__ int wave_sums[BLOCK / 64];
    if ((tid & 63) == 0) wave_sums[tid >> 6] = cnt;
    __syncthreads();
    if (tid == 0)
        partials[blockIdx.x] = (unsigned int)(wave_sums[0] + wave_sums[1] +
                                              wave_sums[2] + wave_sums[3]);
}

// k2: read (L3-hot from k1) + write: out_spikes = (spikes >= 0.5).
__global__ __launch_bounds__(BLOCK) void map_kernel(
    const v4f* __restrict__ in,
    v4f* __restrict__ outv,
    int n4)
{
    const int tid = threadIdx.x;
    int i = blockIdx.x * (BLOCK * 4) + tid;
    for (; i + 3 * BLOCK < n4; i += STEP) {
        v4f a = in[i];
        v4f b = in[i +     BLOCK];
        v4f c = in[i + 2 * BLOCK];
        v4f d = in[i + 3 * BLOCK];
        v4f oa, ob, oc, od;
        spike4(a, oa); spike4(b, ob); spike4(c, oc); spike4(d, od);
        outv[i]             = oa;
        outv[i +     BLOCK] = ob;
        outv[i + 2 * BLOCK] = oc;
        outv[i + 3 * BLOCK] = od;
    }
}

// k3: reduce 512 partials, then read P + write delta = S - P.
__global__ __launch_bounds__(BLOCK) void delta_kernel(
    const v4f* __restrict__ P4,
    v4f* __restrict__ delta4,
    const unsigned int* __restrict__ partials,
    int n4, float inv_n)
{
    const int tid = threadIdx.x;

    int c = (int)partials[tid] + (int)partials[tid + BLOCK];   // GRID = 2*BLOCK
    #pragma unroll
    for (int off = 32; off > 0; off >>= 1)
        c += __shfl_down(c, off, 64);
    __shared__ int wave_sums[BLOCK / 64];
    if ((tid & 63) == 0) wave_sums[tid >> 6] = c;
    __syncthreads();
    const int total = wave_sums[0] + wave_sums[1] + wave_sums[2] + wave_sums[3];
    const float S = (float)total * inv_n;   // exact: total <= 2^25, inv_n = 2^-25

    int i = blockIdx.x * (BLOCK * 4) + tid;
    for (; i + 3 * BLOCK < n4; i += STEP) {
        v4f a = P4[i];
        v4f b = P4[i +     BLOCK];
        v4f c4 = P4[i + 2 * BLOCK];
        v4f d = P4[i + 3 * BLOCK];
        delta4[i]             = S - a;
        delta4[i +     BLOCK] = S - b;
        delta4[i + 2 * BLOCK] = S - c4;
        delta4[i + 3 * BLOCK] = S - d;
    }
}

extern "C" void kernel_launch(void* const* d_in, const int* in_sizes, int n_in,
                              void* d_out, int out_size, void* d_ws, size_t ws_size,
                              hipStream_t stream) {
    const float* spikes = (const float*)d_in[0];
    const float* P      = (const float*)d_in[1];
    float* out          = (float*)d_out;

    const int n  = in_sizes[0];          // 33554432
    const int n4 = n / 4;                // 8388608 = 16 * STEP
    float* delta_out  = out;             // first N floats
    float* spikes_out = out + n;         // second N floats

    unsigned int* partials = (unsigned int*)d_ws;  // GRID u32, fully rewritten

    count_kernel<<<GRID, BLOCK, 0, stream>>>(
        (const v4f*)spikes, partials, n4);

    map_kernel<<<GRID, BLOCK, 0, stream>>>(
        (const v4f*)spikes, (v4f*)spikes_out, n4);

    delta_kernel<<<GRID, BLOCK, 0, stream>>>(
        (const v4f*)P, (v4f*)delta_out, partials, n4, 1.0f / (float)n);
}